// Round 2
// baseline (1652.184 us; speedup 1.0000x reference)
//
#include <hip/hip_runtime.h>
#include <hip/hip_bf16.h>

// Problem constants (from reference): B=512, T=2048, S=16, H=128, A=4
#define HDIM 128
#define SDIM 16
#define ADIM 4
#define NREC 40          // packed per-j weight record, floats (stride 160B, 16B-aligned)
#define NTOK (512 * 2048)
#define TPT 4            // tokens per thread: amortizes the wave-uniform LDS weight
                         // reads (the round-1 bottleneck: LDS pipe is per-CU,
                         // 10x ds_read_b128 per j-iter serialized it at ~345us)

__device__ __forceinline__ float fast_tanh(float x) {
    // tanh(x) = 1 - 2/(1+e^{2x}); safe at +/-inf
    float e = __expf(2.0f * x);
    return 1.0f - 2.0f * __builtin_amdgcn_rcpf(e + 1.0f);
}

__global__ __launch_bounds__(256, 2) void cbf_qp_kernel(
    const float* __restrict__ state,
    const float* __restrict__ Wc1, const float* __restrict__ bc1,
    const float* __restrict__ Wc2, const float* __restrict__ bc2,
    const float* __restrict__ Wh1, const float* __restrict__ bh1,
    const float* __restrict__ wh2, const float* __restrict__ bh2,
    const float* __restrict__ Wf,  const float* __restrict__ bf,
    const float* __restrict__ Wg,  const float* __restrict__ bg,
    float* __restrict__ out)
{
    // ---- LDS weight cache ------------------------------------------------
    __shared__ float rec[HDIM * NREC];   // per-j: Wc1 col(16) | Wh1 col(16) | Wc2 row(4) | bc1,bh1,wh2,pad
    __shared__ float wg_s[SDIM * 64];    // Wg row-major [16][64]
    __shared__ float wf_s[SDIM * SDIM];  // Wf row-major [16][16]
    __shared__ float bg_s[64];
    __shared__ float bf_s[SDIM];
    __shared__ float bc2_s[ADIM];
    __shared__ float bh2_s;

    const int tid = threadIdx.x;
    if (tid < HDIM) {
        const int j = tid;
        #pragma unroll
        for (int k = 0; k < SDIM; ++k) {
            rec[j * NREC + k]        = Wc1[k * HDIM + j];   // column j of Wc1
            rec[j * NREC + 16 + k]   = Wh1[k * HDIM + j];   // column j of Wh1
        }
        #pragma unroll
        for (int a = 0; a < ADIM; ++a) rec[j * NREC + 32 + a] = Wc2[j * ADIM + a];
        rec[j * NREC + 36] = bc1[j];
        rec[j * NREC + 37] = bh1[j];
        rec[j * NREC + 38] = wh2[j];
        rec[j * NREC + 39] = 0.0f;
    } else {
        const int t = tid - HDIM;   // 0..127
        for (int m = t; m < SDIM * 64; m += HDIM) wg_s[m] = Wg[m];
        for (int m = t; m < SDIM * SDIM; m += HDIM) wf_s[m] = Wf[m];
        if (t < 64)      bg_s[t]       = bg[t];
        else if (t < 80) bf_s[t - 64]  = bf[t - 64];
        else if (t < 84) bc2_s[t - 80] = bc2[t - 80];
        else if (t == 84) bh2_s        = bh2[0];
    }
    __syncthreads();

    // ---- per-thread: TPT consecutive tokens -----------------------------
    const int n0 = (blockIdx.x * 256 + tid) * TPT;   // 1024 blocks * 256 * 4 = NTOK

    float sv[TPT][16];
    #pragma unroll
    for (int t = 0; t < TPT; ++t) {
        const float4* sp = reinterpret_cast<const float4*>(state + (size_t)(n0 + t) * SDIM);
        float4 a = sp[0], b = sp[1], c = sp[2], d = sp[3];
        sv[t][0]=a.x;  sv[t][1]=a.y;  sv[t][2]=a.z;  sv[t][3]=a.w;
        sv[t][4]=b.x;  sv[t][5]=b.y;  sv[t][6]=b.z;  sv[t][7]=b.w;
        sv[t][8]=c.x;  sv[t][9]=c.y;  sv[t][10]=c.z; sv[t][11]=c.w;
        sv[t][12]=d.x; sv[t][13]=d.y; sv[t][14]=d.z; sv[t][15]=d.w;
    }

    float ua[TPT][4];
    float hacc[TPT];
    float dh[TPT][16];
    #pragma unroll
    for (int t = 0; t < TPT; ++t) {
        ua[t][0]=0.f; ua[t][1]=0.f; ua[t][2]=0.f; ua[t][3]=0.f;
        hacc[t]=0.f;
        #pragma unroll
        for (int k = 0; k < 16; ++k) dh[t][k] = 0.f;
    }

    #pragma unroll 2
    for (int j = 0; j < HDIM; ++j) {
        const float4* r = reinterpret_cast<const float4*>(&rec[j * NREC]);
        float4 c0 = r[0], c1 = r[1], c2 = r[2], c3 = r[3];   // Wc1 col
        float4 m0 = r[4], m1 = r[5], m2 = r[6], m3 = r[7];   // Wh1 col
        float4 w2 = r[8];                                    // Wc2 row j
        float4 bb = r[9];                                    // bc1, bh1, wh2, pad

        #pragma unroll
        for (int t = 0; t < TPT; ++t) {
            float z1 = bb.x
                + sv[t][0]*c0.x  + sv[t][1]*c0.y  + sv[t][2]*c0.z  + sv[t][3]*c0.w
                + sv[t][4]*c1.x  + sv[t][5]*c1.y  + sv[t][6]*c1.z  + sv[t][7]*c1.w
                + sv[t][8]*c2.x  + sv[t][9]*c2.y  + sv[t][10]*c2.z + sv[t][11]*c2.w
                + sv[t][12]*c3.x + sv[t][13]*c3.y + sv[t][14]*c3.z + sv[t][15]*c3.w;
            float z2 = bb.y
                + sv[t][0]*m0.x  + sv[t][1]*m0.y  + sv[t][2]*m0.z  + sv[t][3]*m0.w
                + sv[t][4]*m1.x  + sv[t][5]*m1.y  + sv[t][6]*m1.z  + sv[t][7]*m1.w
                + sv[t][8]*m2.x  + sv[t][9]*m2.y  + sv[t][10]*m2.z + sv[t][11]*m2.w
                + sv[t][12]*m3.x + sv[t][13]*m3.y + sv[t][14]*m3.z + sv[t][15]*m3.w;

            float t1 = fast_tanh(z1);
            float t2 = fast_tanh(z2);

            ua[t][0] += t1 * w2.x; ua[t][1] += t1 * w2.y;
            ua[t][2] += t1 * w2.z; ua[t][3] += t1 * w2.w;
            hacc[t]  += bb.z * t2;

            float dj = bb.z * (1.0f - t2 * t2);   // wh2[j] * sech^2(z2)
            dh[t][0]  += m0.x * dj; dh[t][1]  += m0.y * dj; dh[t][2]  += m0.z * dj; dh[t][3]  += m0.w * dj;
            dh[t][4]  += m1.x * dj; dh[t][5]  += m1.y * dj; dh[t][6]  += m1.z * dj; dh[t][7]  += m1.w * dj;
            dh[t][8]  += m2.x * dj; dh[t][9]  += m2.y * dj; dh[t][10] += m2.z * dj; dh[t][11] += m2.w * dj;
            dh[t][12] += m3.x * dj; dh[t][13] += m3.y * dj; dh[t][14] += m3.z * dj; dh[t][15] += m3.w * dj;
        }
    }

    // ---- right = h + bh2 + dh . (s @ Wf + bf) ---------------------------
    float right[TPT];
    #pragma unroll
    for (int t = 0; t < TPT; ++t) right[t] = hacc[t] + bh2_s;
    {
        const float4* wf4 = reinterpret_cast<const float4*>(wf_s);
        const float4* bf4 = reinterpret_cast<const float4*>(bf_s);
        #pragma unroll
        for (int i4 = 0; i4 < 4; ++i4) {
            float4 fb = bf4[i4];
            float4 f[TPT];
            #pragma unroll
            for (int t = 0; t < TPT; ++t) f[t] = fb;
            #pragma unroll
            for (int k = 0; k < 16; ++k) {
                float4 w = wf4[k * 4 + i4];   // Wf[k][i4*4 .. i4*4+3]
                #pragma unroll
                for (int t = 0; t < TPT; ++t) {
                    f[t].x += sv[t][k] * w.x; f[t].y += sv[t][k] * w.y;
                    f[t].z += sv[t][k] * w.z; f[t].w += sv[t][k] * w.w;
                }
            }
            #pragma unroll
            for (int t = 0; t < TPT; ++t)
                right[t] += dh[t][i4*4+0]*f[t].x + dh[t][i4*4+1]*f[t].y
                          + dh[t][i4*4+2]*f[t].z + dh[t][i4*4+3]*f[t].w;
        }
    }

    // ---- left[a] = -sum_s dh[s] * g[s][a],  g = s @ Wg + bg -------------
    float l[TPT][4];
    #pragma unroll
    for (int t = 0; t < TPT; ++t) { l[t][0]=0.f; l[t][1]=0.f; l[t][2]=0.f; l[t][3]=0.f; }
    {
        const float4* wg4 = reinterpret_cast<const float4*>(wg_s);
        const float4* bg4 = reinterpret_cast<const float4*>(bg_s);
        #pragma unroll
        for (int si = 0; si < 16; ++si) {
            float4 gb = bg4[si];
            float4 g[TPT];
            #pragma unroll
            for (int t = 0; t < TPT; ++t) g[t] = gb;
            #pragma unroll
            for (int k = 0; k < 16; ++k) {
                float4 w = wg4[k * 16 + si];  // Wg[k][si*4 .. si*4+3]
                #pragma unroll
                for (int t = 0; t < TPT; ++t) {
                    g[t].x += sv[t][k] * w.x; g[t].y += sv[t][k] * w.y;
                    g[t].z += sv[t][k] * w.z; g[t].w += sv[t][k] * w.w;
                }
            }
            #pragma unroll
            for (int t = 0; t < TPT; ++t) {
                float d = dh[t][si];
                l[t][0] -= d * g[t].x; l[t][1] -= d * g[t].y;
                l[t][2] -= d * g[t].z; l[t][3] -= d * g[t].w;
            }
        }
    }

    // ---- closed-form QP + store -----------------------------------------
    #pragma unroll
    for (int t = 0; t < TPT; ++t) {
        float u0 = 2.0f * (ua[t][0] + bc2_s[0]);
        float u1 = 2.0f * (ua[t][1] + bc2_s[1]);
        float u2 = 2.0f * (ua[t][2] + bc2_s[2]);
        float u3 = 2.0f * (ua[t][3] + bc2_s[3]);

        float viol = l[t][0]*u0 + l[t][1]*u1 + l[t][2]*u2 + l[t][3]*u3 - right[t];
        float lsq  = l[t][0]*l[t][0] + l[t][1]*l[t][1] + l[t][2]*l[t][2] + l[t][3]*l[t][3];
        float lam  = viol > 0.0f ? viol / (lsq + 1e-8f) : 0.0f;

        float4 u;
        u.x = u0 - lam * l[t][0];
        u.y = u1 - lam * l[t][1];
        u.z = u2 - lam * l[t][2];
        u.w = u3 - lam * l[t][3];
        reinterpret_cast<float4*>(out)[n0 + t] = u;
    }
}

extern "C" void kernel_launch(void* const* d_in, const int* in_sizes, int n_in,
                              void* d_out, int out_size, void* d_ws, size_t ws_size,
                              hipStream_t stream) {
    (void)in_sizes; (void)n_in; (void)d_ws; (void)ws_size; (void)out_size;
    const float* state = (const float*)d_in[0];
    const float* Wc1   = (const float*)d_in[1];
    const float* bc1   = (const float*)d_in[2];
    const float* Wc2   = (const float*)d_in[3];
    const float* bc2   = (const float*)d_in[4];
    const float* Wh1   = (const float*)d_in[5];
    const float* bh1   = (const float*)d_in[6];
    const float* wh2   = (const float*)d_in[7];
    const float* bh2   = (const float*)d_in[8];
    const float* Wf    = (const float*)d_in[9];
    const float* bf    = (const float*)d_in[10];
    const float* Wg    = (const float*)d_in[11];
    const float* bg    = (const float*)d_in[12];
    float* out = (float*)d_out;

    dim3 grid(NTOK / (256 * TPT));
    dim3 block(256);
    hipLaunchKernelGGL(cbf_qp_kernel, grid, block, 0, stream,
                       state, Wc1, bc1, Wc2, bc2, Wh1, bh1, wh2, bh2,
                       Wf, bf, Wg, bg, out);
}

// Round 4
// 358.130 us; speedup vs baseline: 4.6134x; 4.6134x over previous
//
#include <hip/hip_runtime.h>
#include <hip/hip_bf16.h>

// Problem constants (from reference): B=512, T=2048, S=16, H=128, A=4
#define HDIM 128
#define SDIM 16
#define ADIM 4
#define NREC 40          // packed per-j weight record (floats); 160B stride, 16B-aligned
#define NTOK (512 * 2048)

// d_ws float-offset layout (prepacked by pack_kernel every launch; ws is
// re-poisoned 0xAA before each timed call, so repack unconditionally)
#define REC_OFF  0
#define WF_OFF   (HDIM * NREC)       // 5120 : Wf row-major [16][16]
#define WG_OFF   (WF_OFF + 256)      // 5376 : Wg row-major [16][64]
#define BG_OFF   (WG_OFF + 1024)     // 6400
#define BF_OFF   (BG_OFF + 64)       // 6464
#define BC2_OFF  (BF_OFF + 16)       // 6480
#define BH2_OFF  (BC2_OFF + 4)       // 6484
#define WS_FLOATS 6496

// Constant-address-space loads: all weight indices in the hot loop are
// wave-uniform, so force the compiler to use s_load (SMEM pipe) instead of
// LDS/VMEM. Round-1 was LDS-pipe-bound (10x ds_read_b128 per j-iter,
// ~345us of per-CU LDS serialization); round-2's register batching spilled
// (3.8 GB scratch traffic). Scalar loads cost neither VALU nor LDS.
// NOTE: must use clang ext_vector_type, NOT HIP float4 — HIP_vector_type's
// copy ctor can't bind a generic-AS reference to an AS(4) lvalue (round-3
// compile failure).
typedef float fvec4 __attribute__((ext_vector_type(4)));

__device__ __forceinline__ fvec4 sload4(const float* p) {
    return *(const __attribute__((address_space(4))) fvec4*)(uintptr_t)p;
}
__device__ __forceinline__ float sload1(const float* p) {
    return *(const __attribute__((address_space(4))) float*)(uintptr_t)p;
}

__device__ __forceinline__ float fast_tanh(float x) {
    // tanh(x) = 1 - 2/(1+e^{2x}); safe at +/-inf
    float e = __expf(2.0f * x);
    return 1.0f - 2.0f * __builtin_amdgcn_rcpf(e + 1.0f);
}

__global__ __launch_bounds__(256) void pack_kernel(
    const float* __restrict__ Wc1, const float* __restrict__ bc1,
    const float* __restrict__ Wc2, const float* __restrict__ bc2,
    const float* __restrict__ Wh1, const float* __restrict__ bh1,
    const float* __restrict__ wh2, const float* __restrict__ bh2,
    const float* __restrict__ Wf,  const float* __restrict__ bf,
    const float* __restrict__ Wg,  const float* __restrict__ bg,
    float* __restrict__ ws)
{
    const int tid = threadIdx.x;
    if (tid < HDIM) {
        const int j = tid;
        float* r = ws + REC_OFF + j * NREC;
        #pragma unroll
        for (int k = 0; k < SDIM; ++k) {
            r[k]      = Wc1[k * HDIM + j];   // column j of Wc1
            r[16 + k] = Wh1[k * HDIM + j];   // column j of Wh1
        }
        #pragma unroll
        for (int a = 0; a < ADIM; ++a) r[32 + a] = Wc2[j * ADIM + a];
        r[36] = bc1[j];
        r[37] = bh1[j];
        r[38] = wh2[j];
        r[39] = 0.0f;
    } else {
        const int t = tid - HDIM;   // 0..127
        for (int m = t; m < SDIM * 64; m += HDIM)   ws[WG_OFF + m] = Wg[m];
        for (int m = t; m < SDIM * SDIM; m += HDIM) ws[WF_OFF + m] = Wf[m];
        if (t < 64)       ws[BG_OFF + t]         = bg[t];
        else if (t < 80)  ws[BF_OFF + (t - 64)]  = bf[t - 64];
        else if (t < 84)  ws[BC2_OFF + (t - 80)] = bc2[t - 80];
        else if (t == 84) ws[BH2_OFF]            = bh2[0];
    }
}

__global__ __launch_bounds__(256, 4) void cbf_qp_kernel(
    const float* __restrict__ state,
    const float* __restrict__ ws,
    float* __restrict__ out)
{
    const int tid = threadIdx.x;
    const int n = blockIdx.x * 256 + tid;   // 4096 blocks * 256 = NTOK exactly

    float sv[16];
    {
        const float4* sp = reinterpret_cast<const float4*>(state + (size_t)n * SDIM);
        float4 a = sp[0], b = sp[1], c = sp[2], d = sp[3];
        sv[0]=a.x;  sv[1]=a.y;  sv[2]=a.z;  sv[3]=a.w;
        sv[4]=b.x;  sv[5]=b.y;  sv[6]=b.z;  sv[7]=b.w;
        sv[8]=c.x;  sv[9]=c.y;  sv[10]=c.z; sv[11]=c.w;
        sv[12]=d.x; sv[13]=d.y; sv[14]=d.z; sv[15]=d.w;
    }

    float ua0 = 0.f, ua1 = 0.f, ua2 = 0.f, ua3 = 0.f;   // t1 @ Wc2 accumulator
    float h = 0.f;                                      // t2 . wh2
    float dh[16];
    #pragma unroll
    for (int k = 0; k < 16; ++k) dh[k] = 0.f;

    const float* rec = ws + REC_OFF;

    #pragma unroll 2
    for (int j = 0; j < HDIM; ++j) {
        const float* r = rec + j * NREC;
        fvec4 c0 = sload4(r +  0), c1 = sload4(r +  4), c2 = sload4(r +  8), c3 = sload4(r + 12); // Wc1 col
        fvec4 m0 = sload4(r + 16), m1 = sload4(r + 20), m2 = sload4(r + 24), m3 = sload4(r + 28); // Wh1 col
        fvec4 w2 = sload4(r + 32);                    // Wc2 row j
        fvec4 bb = sload4(r + 36);                    // bc1, bh1, wh2, pad

        float z1 = bb.x
            + sv[0]*c0.x  + sv[1]*c0.y  + sv[2]*c0.z  + sv[3]*c0.w
            + sv[4]*c1.x  + sv[5]*c1.y  + sv[6]*c1.z  + sv[7]*c1.w
            + sv[8]*c2.x  + sv[9]*c2.y  + sv[10]*c2.z + sv[11]*c2.w
            + sv[12]*c3.x + sv[13]*c3.y + sv[14]*c3.z + sv[15]*c3.w;
        float z2 = bb.y
            + sv[0]*m0.x  + sv[1]*m0.y  + sv[2]*m0.z  + sv[3]*m0.w
            + sv[4]*m1.x  + sv[5]*m1.y  + sv[6]*m1.z  + sv[7]*m1.w
            + sv[8]*m2.x  + sv[9]*m2.y  + sv[10]*m2.z + sv[11]*m2.w
            + sv[12]*m3.x + sv[13]*m3.y + sv[14]*m3.z + sv[15]*m3.w;

        float t1 = fast_tanh(z1);
        float t2 = fast_tanh(z2);

        ua0 += t1 * w2.x; ua1 += t1 * w2.y; ua2 += t1 * w2.z; ua3 += t1 * w2.w;
        h   += bb.z * t2;

        float dj = bb.z * (1.0f - t2 * t2);   // wh2[j] * sech^2(z2)
        dh[0]  += m0.x * dj; dh[1]  += m0.y * dj; dh[2]  += m0.z * dj; dh[3]  += m0.w * dj;
        dh[4]  += m1.x * dj; dh[5]  += m1.y * dj; dh[6]  += m1.z * dj; dh[7]  += m1.w * dj;
        dh[8]  += m2.x * dj; dh[9]  += m2.y * dj; dh[10] += m2.z * dj; dh[11] += m2.w * dj;
        dh[12] += m3.x * dj; dh[13] += m3.y * dj; dh[14] += m3.z * dj; dh[15] += m3.w * dj;
    }

    // ---- right = h + bh2 + dh . (s @ Wf + bf) ---------------------------
    float right = h + sload1(ws + BH2_OFF);
    {
        #pragma unroll
        for (int i4 = 0; i4 < 4; ++i4) {
            fvec4 f = sload4(ws + BF_OFF + i4 * 4);
            #pragma unroll
            for (int k = 0; k < 16; ++k) {
                fvec4 w = sload4(ws + WF_OFF + (k * 4 + i4) * 4);  // Wf[k][i4*4..+3]
                f.x += sv[k] * w.x; f.y += sv[k] * w.y;
                f.z += sv[k] * w.z; f.w += sv[k] * w.w;
            }
            right += dh[i4*4+0]*f.x + dh[i4*4+1]*f.y + dh[i4*4+2]*f.z + dh[i4*4+3]*f.w;
        }
    }

    // ---- left[a] = -sum_s dh[s] * g[s][a],  g = s @ Wg + bg -------------
    float l0 = 0.f, l1 = 0.f, l2v = 0.f, l3 = 0.f;
    {
        #pragma unroll
        for (int si = 0; si < 16; ++si) {
            fvec4 g = sload4(ws + BG_OFF + si * 4);
            #pragma unroll
            for (int k = 0; k < 16; ++k) {
                fvec4 w = sload4(ws + WG_OFF + (k * 16 + si) * 4);  // Wg[k][si*4..+3]
                g.x += sv[k] * w.x; g.y += sv[k] * w.y;
                g.z += sv[k] * w.z; g.w += sv[k] * w.w;
            }
            float d = dh[si];
            l0 -= d * g.x; l1 -= d * g.y; l2v -= d * g.z; l3 -= d * g.w;
        }
    }

    // ---- closed-form QP --------------------------------------------------
    float u0 = 2.0f * (ua0 + sload1(ws + BC2_OFF + 0));
    float u1 = 2.0f * (ua1 + sload1(ws + BC2_OFF + 1));
    float u2 = 2.0f * (ua2 + sload1(ws + BC2_OFF + 2));
    float u3 = 2.0f * (ua3 + sload1(ws + BC2_OFF + 3));

    float viol = l0*u0 + l1*u1 + l2v*u2 + l3*u3 - right;
    float lsq  = l0*l0 + l1*l1 + l2v*l2v + l3*l3;
    float lam  = viol > 0.0f ? viol / (lsq + 1e-8f) : 0.0f;

    float4 u;
    u.x = u0 - lam * l0;
    u.y = u1 - lam * l1;
    u.z = u2 - lam * l2v;
    u.w = u3 - lam * l3;
    reinterpret_cast<float4*>(out)[n] = u;
}

extern "C" void kernel_launch(void* const* d_in, const int* in_sizes, int n_in,
                              void* d_out, int out_size, void* d_ws, size_t ws_size,
                              hipStream_t stream) {
    (void)in_sizes; (void)n_in; (void)ws_size; (void)out_size;
    const float* state = (const float*)d_in[0];
    const float* Wc1   = (const float*)d_in[1];
    const float* bc1   = (const float*)d_in[2];
    const float* Wc2   = (const float*)d_in[3];
    const float* bc2   = (const float*)d_in[4];
    const float* Wh1   = (const float*)d_in[5];
    const float* bh1   = (const float*)d_in[6];
    const float* wh2   = (const float*)d_in[7];
    const float* bh2   = (const float*)d_in[8];
    const float* Wf    = (const float*)d_in[9];
    const float* bf    = (const float*)d_in[10];
    const float* Wg    = (const float*)d_in[11];
    const float* bg    = (const float*)d_in[12];
    float* ws  = (float*)d_ws;
    float* out = (float*)d_out;

    hipLaunchKernelGGL(pack_kernel, dim3(1), dim3(256), 0, stream,
                       Wc1, bc1, Wc2, bc2, Wh1, bh1, wh2, bh2,
                       Wf, bf, Wg, bg, ws);

    hipLaunchKernelGGL(cbf_qp_kernel, dim3(NTOK / 256), dim3(256), 0, stream,
                       state, ws, out);
}

// Round 6
// 286.857 us; speedup vs baseline: 5.7596x; 1.2485x over previous
//
#include <hip/hip_runtime.h>
#include <hip/hip_bf16.h>

// B=512, T=2048, S=16, H=128, A=4.  NTOK = 1,048,576 tokens.
// Transposed MFMA chain, v_mfma_f32_16x16x16f16 (K=16: D layout == B layout,
// so chained GEMMs need no data movement; tokens live in lanes).
// Precision plan (round-5 failed at absmax 1.0 = QP-boundary amplification
// ~3e3x of f16 noise): the dh/G/f/z2 chain uses split-f16 (hi+lo, 3 MFMAs
// per product, ~2^-22 rel err); the u_unc chain (z1->ua) has O(1)
// sensitivity and stays single f16.
#define HDIM 128
#define SDIM 16
#define ADIM 4
#define NTOK (512 * 2048)
#define NTILE (NTOK / 16)      // 65536 16-token tiles
#define NBLK 2048
#define WPB 4
#define NWAVE (NBLK * WPB)     // 8192 waves
#define TPW (NTILE / NWAVE)    // 8 tiles per wave

// d_ws byte offsets: half4 A-frags [chunk][lane] (8 B/entry)
#define AZ1   0                // Wc1^T hi          8 chunks (low-prec path)
#define AUA   4096             // Wc2^T hi          8 chunks (rows>=4 zero)
#define AZ2H  8192             // Wh1^T hi          8 chunks
#define AZ2L  12288            // Wh1^T lo
#define ADHH  16384            // (Wh1 .* wh2) hi   8 chunks
#define ADHL  20480            // (Wh1 .* wh2) lo
#define AFH   24576            // Wf^T hi           1 chunk
#define AFL   25088            // Wf^T lo
#define AGH   25600            // Wg^T permuted hi  4 chunks (chunk a: A[s][k]=Wg[k][s*4+a])
#define AGL   27648            // Wg^T permuted lo
#define BGT   29696            // bgt[a][s] = bg[s*4+a]  (64 floats)

typedef _Float16 half4 __attribute__((ext_vector_type(4)));
typedef float f32x4 __attribute__((ext_vector_type(4)));

__device__ __forceinline__ f32x4 mm(half4 a, half4 b, f32x4 c) {
    return __builtin_amdgcn_mfma_f32_16x16x16f16(a, b, c, 0, 0, 0);
}
__device__ __forceinline__ float fast_tanh(float x) {
    float e = __expf(2.0f * x);
    return 1.0f - 2.0f * __builtin_amdgcn_rcpf(e + 1.0f);
}
__device__ __forceinline__ f32x4 tanh4(f32x4 z) {
    f32x4 r;
    r.x = fast_tanh(z.x); r.y = fast_tanh(z.y);
    r.z = fast_tanh(z.z); r.w = fast_tanh(z.w);
    return r;
}
__device__ __forceinline__ half4 toh(f32x4 v) {
    half4 h;
    h.x = (_Float16)v.x; h.y = (_Float16)v.y;
    h.z = (_Float16)v.z; h.w = (_Float16)v.w;
    return h;
}
// split fp32 vector into f16 hi + f16 lo (x ~= hi + lo, residual ~2^-22 x)
__device__ __forceinline__ void split4(f32x4 v, half4& hi, half4& lo) {
    hi = toh(v);
    f32x4 r;
    r.x = v.x - (float)hi.x; r.y = v.y - (float)hi.y;
    r.z = v.z - (float)hi.z; r.w = v.w - (float)hi.w;
    lo = toh(r);
}
__device__ __forceinline__ float dot4(f32x4 a, f32x4 b) {
    return a.x*b.x + a.y*b.y + a.z*b.z + a.w*b.w;
}
__device__ __forceinline__ float redq(float v) {   // sum over the 4 lane-quads
    v += __shfl_xor(v, 16, 64);
    v += __shfl_xor(v, 32, 64);
    return v;
}

__global__ __launch_bounds__(256) void pack_kernel(
    const float* __restrict__ Wc1, const float* __restrict__ Wc2,
    const float* __restrict__ Wh1, const float* __restrict__ wh2,
    const float* __restrict__ Wf,  const float* __restrict__ Wg,
    const float* __restrict__ bg,  char* __restrict__ wsb)
{
    _Float16* az1  = (_Float16*)(wsb + AZ1);
    _Float16* aua  = (_Float16*)(wsb + AUA);
    _Float16* az2h = (_Float16*)(wsb + AZ2H);
    _Float16* az2l = (_Float16*)(wsb + AZ2L);
    _Float16* adhh = (_Float16*)(wsb + ADHH);
    _Float16* adhl = (_Float16*)(wsb + ADHL);
    _Float16* afh  = (_Float16*)(wsb + AFH);
    _Float16* afl  = (_Float16*)(wsb + AFL);
    _Float16* agh  = (_Float16*)(wsb + AGH);
    _Float16* agl  = (_Float16*)(wsb + AGL);
    float*    bgt  = (float*)(wsb + BGT);
    const int tid = threadIdx.x;

    // A-frag layout: lane l holds A[m][k], m = l&15, k = (l>>4)*4 + e
    for (int idx = tid; idx < 8 * 64; idx += 256) {
        const int c = idx >> 6, lane = idx & 63;
        const int m = lane & 15, q = lane >> 4;
        #pragma unroll
        for (int e = 0; e < 4; ++e) {
            const int k = q * 4 + e;        // K index within chunk
            const int j = c * 16 + k;       // global hidden index (for ua/dh)
            az1[idx*4+e] = (_Float16)Wc1[k * HDIM + c*16 + m];
            aua[idx*4+e] = (m < ADIM) ? (_Float16)Wc2[j * ADIM + m] : (_Float16)0.f;
            {   // Wh1^T split
                float w = Wh1[k * HDIM + c*16 + m];
                _Float16 h = (_Float16)w;
                az2h[idx*4+e] = h;
                az2l[idx*4+e] = (_Float16)(w - (float)h);
            }
            {   // (Wh1 .* wh2) split  (A[m=s][k]: row s, col j)
                float w = Wh1[m * HDIM + j] * wh2[j];
                _Float16 h = (_Float16)w;
                adhh[idx*4+e] = h;
                adhl[idx*4+e] = (_Float16)(w - (float)h);
            }
        }
    }
    if (tid < 64) {                                  // Wf^T split
        const int m = tid & 15, q = tid >> 4;
        #pragma unroll
        for (int e = 0; e < 4; ++e) {
            float w = Wf[(q*4+e) * SDIM + m];
            _Float16 h = (_Float16)w;
            afh[tid*4+e] = h;
            afl[tid*4+e] = (_Float16)(w - (float)h);
        }
    }
    for (int idx = tid; idx < 4 * 64; idx += 256) {  // Wg^T row-permuted split
        const int a = idx >> 6, lane = idx & 63;
        const int m = lane & 15, q = lane >> 4;      // m = s index
        #pragma unroll
        for (int e = 0; e < 4; ++e) {
            float w = Wg[(q*4+e) * 64 + m*4 + a];
            _Float16 h = (_Float16)w;
            agh[idx*4+e] = h;
            agl[idx*4+e] = (_Float16)(w - (float)h);
        }
    }
    if (tid < 64) {                                  // bgt[a][s] = bg[s*4+a]
        const int a = tid >> 4, s = tid & 15;
        bgt[a*16 + s] = bg[s*4 + a];
    }
}

__global__ __launch_bounds__(256) void cbf_qp_kernel(
    const float* __restrict__ state,
    const float* __restrict__ bc1, const float* __restrict__ bc2,
    const float* __restrict__ bh1, const float* __restrict__ wh2,
    const float* __restrict__ bh2, const float* __restrict__ bf,
    const char* __restrict__ wsb,  float* __restrict__ out)
{
    const int tid  = threadIdx.x;
    const int lane = tid & 63;
    const int q = lane >> 4, n = lane & 15;
    const int wid = blockIdx.x * WPB + (tid >> 6);

    // ---- persistent per-lane weight A-frags (loaded once, reused 8 tiles) ----
    const half4* pz1  = (const half4*)(wsb + AZ1);
    const half4* pua  = (const half4*)(wsb + AUA);
    const half4* pz2h = (const half4*)(wsb + AZ2H);
    const half4* pz2l = (const half4*)(wsb + AZ2L);
    const half4* pdhh = (const half4*)(wsb + ADHH);
    const half4* pdhl = (const half4*)(wsb + ADHL);
    half4 az1[8], aua[8], az2h[8], az2l[8], adhh[8], adhl[8];
    #pragma unroll
    for (int c = 0; c < 8; ++c) {
        az1[c]  = pz1[c*64 + lane];
        aua[c]  = pua[c*64 + lane];
        az2h[c] = pz2h[c*64 + lane];
        az2l[c] = pz2l[c*64 + lane];
        adhh[c] = pdhh[c*64 + lane];
        adhl[c] = pdhl[c*64 + lane];
    }
    half4 afh = ((const half4*)(wsb + AFH))[lane];
    half4 afl = ((const half4*)(wsb + AFL))[lane];
    half4 agh[4], agl[4];
    #pragma unroll
    for (int a = 0; a < 4; ++a) {
        agh[a] = ((const half4*)(wsb + AGH))[a*64 + lane];
        agl[a] = ((const half4*)(wsb + AGL))[a*64 + lane];
    }

    // C-init frags (biases; broadcast over tokens since D rows are the M axis)
    f32x4 bfC = *(const f32x4*)(bf + q*4);
    f32x4 uaC;
    {
        f32x4 b2 = *(const f32x4*)(bc2);
        uaC.x = q == 0 ? b2.x : 0.f; uaC.y = q == 0 ? b2.y : 0.f;
        uaC.z = q == 0 ? b2.z : 0.f; uaC.w = q == 0 ? b2.w : 0.f;
    }
    const float* bgt = (const float*)(wsb + BGT);
    f32x4 bgC0 = *(const f32x4*)(bgt + 0*16 + q*4);
    f32x4 bgC1 = *(const f32x4*)(bgt + 1*16 + q*4);
    f32x4 bgC2 = *(const f32x4*)(bgt + 2*16 + q*4);
    f32x4 bgC3 = *(const f32x4*)(bgt + 3*16 + q*4);
    const float bh2v = bh2[0];

    for (int it = 0; it < TPW; ++it) {
        const int tile = wid * TPW + it;
        // B-frag of state^T: lane(q,n) holds state[token n][q*4 .. q*4+3]
        f32x4 sv = *(const f32x4*)(state + (size_t)(tile*16 + n) * SDIM + q*4);
        half4 bsh, bsl;
        split4(sv, bsh, bsl);

        f32x4 ua = uaC;                    // ua^T accum (rows 0-3 = a)
        f32x4 dh = {0.f, 0.f, 0.f, 0.f};   // dh^T accum (rows = s)
        float hp = 0.f;                    // h partial (reduced over q later)
        #pragma unroll
        for (int c = 0; c < 8; ++c) {
            // ---- low-precision chain: z1 -> tanh -> ua  (O(1) sensitivity)
            f32x4 b1 = *(const f32x4*)(bc1 + c*16 + q*4);
            f32x4 z1 = mm(az1[c], bsh, b1);
            half4 t1h = toh(tanh4(z1));
            ua = mm(aua[c], t1h, ua);

            // ---- high-precision chain: z2 (split x split, 3 MFMAs)
            f32x4 b2 = *(const f32x4*)(bh1 + c*16 + q*4);
            f32x4 z2 = mm(az2h[c], bsl, b2);
            z2 = mm(az2l[c], bsh, z2);
            z2 = mm(az2h[c], bsh, z2);
            f32x4 t2 = tanh4(z2);
            f32x4 s2;
            s2.x = 1.f - t2.x*t2.x; s2.y = 1.f - t2.y*t2.y;
            s2.z = 1.f - t2.z*t2.z; s2.w = 1.f - t2.w*t2.w;
            half4 s2h, s2l;
            split4(s2, s2h, s2l);
            dh = mm(adhh[c], s2l, dh);
            dh = mm(adhl[c], s2h, dh);
            dh = mm(adhh[c], s2h, dh);

            f32x4 wv = *(const f32x4*)(wh2 + c*16 + q*4);
            hp += dot4(wv, t2);
        }
        // f^T (rows = s) and G chunks (chunk a: row s = g[s][a]) — split path
        f32x4 fD = mm(afh, bsl, bfC);
        fD = mm(afl, bsh, fD);
        fD = mm(afh, bsh, fD);
        f32x4 G0 = mm(agh[0], bsl, bgC0); G0 = mm(agl[0], bsh, G0); G0 = mm(agh[0], bsh, G0);
        f32x4 G1 = mm(agh[1], bsl, bgC1); G1 = mm(agl[1], bsh, G1); G1 = mm(agh[1], bsh, G1);
        f32x4 G2 = mm(agh[2], bsl, bgC2); G2 = mm(agl[2], bsh, G2); G2 = mm(agh[2], bsh, G2);
        f32x4 G3 = mm(agh[3], bsl, bgC3); G3 = mm(agl[3], bsh, G3); G3 = mm(agh[3], bsh, G3);

        // right = h + bh2 + dh.f   (partials live in lane-quads; reduce)
        float right = redq(hp + dot4(dh, fD)) + bh2v;
        float l0 = -redq(dot4(dh, G0));
        float l1 = -redq(dot4(dh, G1));
        float l2 = -redq(dot4(dh, G2));
        float l3 = -redq(dot4(dh, G3));
        // ua rows >= 4 are zero, so quad-reduce == broadcast of rows 0-3
        float u0 = 2.f * redq(ua.x);
        float u1 = 2.f * redq(ua.y);
        float u2 = 2.f * redq(ua.z);
        float u3 = 2.f * redq(ua.w);

        float viol = l0*u0 + l1*u1 + l2*u2 + l3*u3 - right;
        float lsq  = l0*l0 + l1*l1 + l2*l2 + l3*l3;
        float lam  = viol > 0.f ? viol / (lsq + 1e-8f) : 0.f;

        if (q == 0) {                      // lanes 0-15 store their token
            f32x4 uo;
            uo.x = u0 - lam*l0; uo.y = u1 - lam*l1;
            uo.z = u2 - lam*l2; uo.w = u3 - lam*l3;
            *(f32x4*)(out + (size_t)(tile*16 + n) * ADIM) = uo;
        }
    }
}

extern "C" void kernel_launch(void* const* d_in, const int* in_sizes, int n_in,
                              void* d_out, int out_size, void* d_ws, size_t ws_size,
                              hipStream_t stream) {
    (void)in_sizes; (void)n_in; (void)ws_size; (void)out_size;
    const float* state = (const float*)d_in[0];
    const float* Wc1   = (const float*)d_in[1];
    const float* bc1   = (const float*)d_in[2];
    const float* Wc2   = (const float*)d_in[3];
    const float* bc2   = (const float*)d_in[4];
    const float* Wh1   = (const float*)d_in[5];
    const float* bh1   = (const float*)d_in[6];
    const float* wh2   = (const float*)d_in[7];
    const float* bh2   = (const float*)d_in[8];
    const float* Wf    = (const float*)d_in[9];
    const float* bf    = (const float*)d_in[10];
    const float* Wg    = (const float*)d_in[11];
    const float* bg    = (const float*)d_in[12];
    float* out = (float*)d_out;

    hipLaunchKernelGGL(pack_kernel, dim3(1), dim3(256), 0, stream,
                       Wc1, Wc2, Wh1, wh2, Wf, Wg, bg, (char*)d_ws);
    hipLaunchKernelGGL(cbf_qp_kernel, dim3(NBLK), dim3(256), 0, stream,
                       state, bc1, bc2, bh1, wh2, bh2, bf,
                       (const char*)d_ws, out);
}